// Round 2
// baseline (386.671 us; speedup 1.0000x reference)
//
#include <hip/hip_runtime.h>
#include <hip/hip_bf16.h>

// Problem constants: B=4, S=1024, DIM=2048, H=32, KVH=8, D=64, REP=4
// qkv fused layout per row (4096 rows): [Q: h*64+d (0..2047) | K: 2048+hk*64+d | V: 2560+hk*64+d]

#define DEVINL __device__ __forceinline__

typedef __attribute__((ext_vector_type(8))) short    bf16x8;
typedef __attribute__((ext_vector_type(4))) short    bf16x4;
typedef __attribute__((ext_vector_type(4))) float    f32x4;
typedef __attribute__((ext_vector_type(8))) unsigned short u16x8;

DEVINL unsigned short f2bf(float f) {            // RNE fp32 -> bf16
  unsigned u = __float_as_uint(f);
  u += 0x7FFFu + ((u >> 16) & 1u);
  return (unsigned short)(u >> 16);
}
DEVINL float bf2f(unsigned short h) { return __uint_as_float((unsigned)h << 16); }

DEVINL void gload_lds16(const void* g, void* l) {  // async global->LDS, 16B/lane
  __builtin_amdgcn_global_load_lds((const __attribute__((address_space(1))) void*)g,
                                   (__attribute__((address_space(3))) void*)l, 16, 0, 0);
}

// ---------------- fp32 -> bf16 convert (x), 8 elems/thread ----------------
__global__ __launch_bounds__(256) void k_cvt_bf16(const float* __restrict__ in,
                                                  unsigned short* __restrict__ out) {
  long long i = (long long)blockIdx.x * 256 + threadIdx.x;
  const float4* p = (const float4*)(in + i * 8);
  float4 a = p[0], b = p[1];
  u16x8 r = { f2bf(a.x), f2bf(a.y), f2bf(a.z), f2bf(a.w),
              f2bf(b.x), f2bf(b.y), f2bf(b.z), f2bf(b.w) };
  *(u16x8*)(out + i * 8) = r;
}

// ------------- weight transpose+convert: fp32 (K,N) -> bf16 (N,K) -------------
__global__ __launch_bounds__(256) void k_transpose_w(const float* __restrict__ in,
                                                     unsigned short* __restrict__ out,
                                                     int K, int N) {
  __shared__ float tile[32][33];                  // +1 pad: conflict-free transpose
  int ntiles = N >> 5;
  int bx = blockIdx.x % ntiles, by = blockIdx.x / ntiles;
  int tx = threadIdx.x & 31, ty = threadIdx.x >> 5;
  int n0 = bx * 32, k0 = by * 32;
#pragma unroll
  for (int i = 0; i < 32; i += 8) tile[ty + i][tx] = in[(long long)(k0 + ty + i) * N + n0 + tx];
  __syncthreads();
#pragma unroll
  for (int i = 0; i < 32; i += 8) out[(long long)(n0 + ty + i) * K + k0 + tx] = f2bf(tile[tx][ty + i]);
}

// ------------- RoPE in-place on qkv rows: Q cols 0..2047, K cols 2048..2559 -------------
__global__ __launch_bounds__(256) void k_rope(unsigned short* __restrict__ qkv,
                                              const float* __restrict__ cosT,
                                              const float* __restrict__ sinT) {
  int idx = blockIdx.x * 256 + threadIdx.x;       // 4096 rows * 320 chunks of 8 cols
  int row = idx / 320;
  int c8  = (idx % 320) * 8;
  int s   = row & 1023;
  int i0  = (c8 & 63) >> 1;                       // pair index within head (4 pairs/chunk)
  unsigned short* p = qkv + (long long)row * 3072 + c8;
  u16x8 v = *(u16x8*)p;
  float4 cv = *(const float4*)&cosT[s * 32 + i0];
  float4 sv = *(const float4*)&sinT[s * 32 + i0];
  float cc[4] = {cv.x, cv.y, cv.z, cv.w};
  float ss[4] = {sv.x, sv.y, sv.z, sv.w};
  u16x8 o;
#pragma unroll
  for (int j = 0; j < 4; j++) {
    float a = bf2f((unsigned short)v[2 * j]), b = bf2f((unsigned short)v[2 * j + 1]);
    o[2 * j]     = (short)f2bf(a * cc[j] - b * ss[j]);
    o[2 * j + 1] = (short)f2bf(a * ss[j] + b * cc[j]);
  }
  *(u16x8*)p = o;
}

// ------------- m97-style GEMM: C[M,N] = A[M,K] * Bt[N,K]^T, 128x128 tile, BK=32 -------------
template <int F32OUT>
__global__ __launch_bounds__(256) void k_gemm_bt(const unsigned short* __restrict__ A,
                                                 const unsigned short* __restrict__ Bt,
                                                 void* __restrict__ Cout, int N, int K) {
  __shared__ unsigned short As[128 * 32];
  __shared__ unsigned short Bs[128 * 32];
  int nbn = N >> 7;
  int bm = (blockIdx.x / nbn) << 7, bn = (blockIdx.x % nbn) << 7;
  int t = threadIdx.x, w = t >> 6, l = t & 63, g = l >> 4, lr = l & 15;
  int wm = (w >> 1) << 6, wn = (w & 1) << 6;
  f32x4 acc[4][4] = {};
  const unsigned short* Ab = A + (long long)bm * K;
  const unsigned short* Bb = Bt + (long long)bn * K;
  for (int k0 = 0; k0 < K; k0 += 32) {
    __syncthreads();
#pragma unroll
    for (int i = 0; i < 2; i++) {                  // 2 insts each for A,B: 4KB per inst
      int e = i * 2048 + t * 8;
      int row = e >> 5, col = e & 31;
      gload_lds16(Ab + (long long)row * K + k0 + col, (char*)As + i * 4096 + w * 1024);
      gload_lds16(Bb + (long long)row * K + k0 + col, (char*)Bs + i * 4096 + w * 1024);
    }
    __syncthreads();                               // drains vmcnt -> tiles ready
    bf16x8 a[4], b[4];
#pragma unroll
    for (int mi = 0; mi < 4; mi++) a[mi] = *(const bf16x8*)&As[(wm + mi * 16 + lr) * 32 + g * 8];
#pragma unroll
    for (int ni = 0; ni < 4; ni++) b[ni] = *(const bf16x8*)&Bs[(wn + ni * 16 + lr) * 32 + g * 8];
#pragma unroll
    for (int mi = 0; mi < 4; mi++)
#pragma unroll
      for (int ni = 0; ni < 4; ni++)
        acc[mi][ni] = __builtin_amdgcn_mfma_f32_16x16x32_bf16(a[mi], b[ni], acc[mi][ni], 0, 0, 0);
  }
#pragma unroll
  for (int mi = 0; mi < 4; mi++)
#pragma unroll
    for (int ni = 0; ni < 4; ni++)
#pragma unroll
      for (int r = 0; r < 4; r++) {
        int row = bm + wm + mi * 16 + g * 4 + r;   // C/D: col=lane&15, row=(lane>>4)*4+r
        int col = bn + wn + ni * 16 + lr;
        if (F32OUT) ((float*)Cout)[(long long)row * N + col] = acc[mi][ni][r];
        else ((unsigned short*)Cout)[(long long)row * N + col] = f2bf(acc[mi][ni][r]);
      }
}

// ------------- causal GQA flash attention, 64-q block, 4 waves x 16 q-rows -------------
// S^T = mfma(K,Q) so P lands lane-local for PV (zero-shuffle chain).
// ROUND-1 BISECT: K read direct from global (no LDS/swizzle); V frags via plain
// scalar ds_read from the dt-panel layout (no ds_read_b64_tr_b16).
__global__ __launch_bounds__(256) void k_attn(const unsigned short* __restrict__ qkv,
                                              unsigned short* __restrict__ outO) {
  __shared__ unsigned short Vs[64 * 64];   // dt-panel: [dt=4][key=64][c=16]
  int t = threadIdx.x, w = t >> 6, l = t & 63, g = l >> 4, c = l & 15;
  int qb = blockIdx.x & 15;
  int h  = (blockIdx.x >> 4) & 31;
  int b  = blockIdx.x >> 9;
  int hk = h >> 2;                                   // GQA: 4 q-heads per kv-head
  const unsigned short* Qb = qkv + (long long)(b * 1024 + qb * 64) * 3072 + h * 64;
  const unsigned short* Kb = qkv + (long long)(b * 1024) * 3072 + 2048 + hk * 64;
  const unsigned short* Vb = qkv + (long long)(b * 1024) * 3072 + 2560 + hk * 64;
  int qrow = w * 16 + c;
  bf16x8 q0 = *(const bf16x8*)(Qb + (long long)qrow * 3072 + g * 8);        // d 0..31
  bf16x8 q1 = *(const bf16x8*)(Qb + (long long)qrow * 3072 + 32 + g * 8);   // d 32..63
  f32x4 acc[4] = {};
  float m = -1e30f, lsum = 0.f;
  const float SC = 0.125f * 1.44269504f;             // scale * log2(e)
  int qglob = qb * 64 + qrow;
  for (int kvt = 0; kvt <= qb; ++kvt) {
    // ---- stage V only (dt-panels), 16B vector writes ----
#pragma unroll
    for (int i = 0; i < 2; i++) {
      int idx = t + i * 256;
      int krow = idx >> 3, c0 = (idx & 7) * 8;
      bf16x8 vv = *(const bf16x8*)(Vb + (long long)(kvt * 64 + krow) * 3072 + c0);
      *(bf16x8*)&Vs[(c0 >> 4) * 1024 + krow * 16 + (c0 & 15)] = vv;
    }
    __syncthreads();
    // ---- scores S^T[key][q]: A=K-frag (direct global), B=Q-frag ----
    float p[16];
    float tmax = -1e30f;
#pragma unroll
    for (int kc = 0; kc < 4; kc++) {
      const unsigned short* Kr = Kb + (long long)(kvt * 64 + kc * 16 + c) * 3072;
      bf16x8 k0 = *(const bf16x8*)(Kr + g * 8);
      bf16x8 k1 = *(const bf16x8*)(Kr + 32 + g * 8);
      f32x4 s4 = {0.f, 0.f, 0.f, 0.f};
      s4 = __builtin_amdgcn_mfma_f32_16x16x32_bf16(k0, q0, s4, 0, 0, 0);
      s4 = __builtin_amdgcn_mfma_f32_16x16x32_bf16(k1, q1, s4, 0, 0, 0);
#pragma unroll
      for (int r = 0; r < 4; r++) {
        int key = kvt * 64 + kc * 16 + g * 4 + r;
        float sv = (key > qglob) ? -1e30f : s4[r];   // causal (no-op for kvt<qb)
        p[kc * 4 + r] = sv;
        tmax = fmaxf(tmax, sv);
      }
    }
    tmax = fmaxf(tmax, __shfl_xor(tmax, 16));        // reduce over key-groups
    tmax = fmaxf(tmax, __shfl_xor(tmax, 32));
    float mnew = fmaxf(m, tmax);
    float fac = exp2f((m - mnew) * SC);
    float ps = 0.f;
    unsigned short pb[16];
#pragma unroll
    for (int i2 = 0; i2 < 16; i2++) {
      float e = exp2f((p[i2] - mnew) * SC);
      ps += e;
      pb[i2] = f2bf(e);
    }
    ps += __shfl_xor(ps, 16);
    ps += __shfl_xor(ps, 32);
    lsum = lsum * fac + ps;
    m = mnew;
    // rescale acc: acc row r is q-local g*4+r; its factor lives at lane g*4+r (c==q)
#pragma unroll
    for (int r = 0; r < 4; r++) {
      float fr = __shfl(fac, g * 4 + r);
#pragma unroll
      for (int dt = 0; dt < 4; dt++) acc[dt][r] *= fr;
    }
    // ---- PV: scalar-gather V frags from panels; virtual-k permutation matches pa ----
    // Need v8[reg] = V[key(g*8+reg)][dt*16+c], key(g*8+j') = kp*32 + (j'<4 ? 4g+j' : 16+4g+j'-4)
#pragma unroll
    for (int kp = 0; kp < 2; kp++) {
      bf16x8 pa;
#pragma unroll
      for (int j = 0; j < 8; j++) pa[j] = (short)pb[kp * 8 + j];
#pragma unroll
      for (int dt = 0; dt < 4; dt++) {
        bf16x8 v8;
#pragma unroll
        for (int j = 0; j < 4; j++) {
          v8[j]     = (short)Vs[dt * 1024 + ((2 * kp) * 16 + 4 * g + j) * 16 + c];
          v8[4 + j] = (short)Vs[dt * 1024 + ((2 * kp + 1) * 16 + 4 * g + j) * 16 + c];
        }
        acc[dt] = __builtin_amdgcn_mfma_f32_16x16x32_bf16(pa, v8, acc[dt], 0, 0, 0);
      }
    }
    __syncthreads();                                  // protect LDS before next stage
  }
  // ---- epilogue: normalize rows, write bf16 (B,S,H*D) ----
#pragma unroll
  for (int r = 0; r < 4; r++) {
    float li = 1.f / __shfl(lsum, g * 4 + r);
    int qg = qb * 64 + w * 16 + g * 4 + r;
#pragma unroll
    for (int dt = 0; dt < 4; dt++)
      outO[(long long)(b * 1024 + qg) * 2048 + h * 64 + dt * 16 + c] = f2bf(acc[dt][r] * li);
  }
}

extern "C" void kernel_launch(void* const* d_in, const int* in_sizes, int n_in,
                              void* d_out, int out_size, void* d_ws, size_t ws_size,
                              hipStream_t stream) {
  const float* x  = (const float*)d_in[0];
  const float* fc = (const float*)d_in[1];
  const float* fs = (const float*)d_in[2];
  const float* wq = (const float*)d_in[3];
  const float* wk = (const float*)d_in[4];
  const float* wv = (const float*)d_in[5];
  const float* wo = (const float*)d_in[6];
  float* out = (float*)d_out;

  // ws layout (bf16 elems), total ~76 MiB
  unsigned short* xb    = (unsigned short*)d_ws;                  // 4096x2048
  unsigned short* wqkvT = xb + (size_t)4096 * 2048;               // 3072x2048 (wq^T|wk^T|wv^T)
  unsigned short* woT   = wqkvT + (size_t)3072 * 2048;            // 2048x2048
  unsigned short* qkv   = woT + (size_t)2048 * 2048;              // 4096x3072
  unsigned short* attnO = qkv + (size_t)4096 * 3072;              // 4096x2048

  k_cvt_bf16<<<4096, 256, 0, stream>>>(x, xb);                    // 8M elems
  k_transpose_w<<<4096, 256, 0, stream>>>(wq, wqkvT, 2048, 2048);
  k_transpose_w<<<1024, 256, 0, stream>>>(wk, wqkvT + (size_t)2048 * 2048, 2048, 512);
  k_transpose_w<<<1024, 256, 0, stream>>>(wv, wqkvT + (size_t)2560 * 2048, 2048, 512);
  k_transpose_w<<<4096, 256, 0, stream>>>(wo, woT, 2048, 2048);
  k_gemm_bt<0><<<32 * 24, 256, 0, stream>>>(xb, wqkvT, qkv, 3072, 2048);   // QKV proj
  k_rope<<<5120, 256, 0, stream>>>(qkv, fc, fs);
  k_attn<<<2048, 256, 0, stream>>>(qkv, attnO);                   // (B*H*16) blocks
  k_gemm_bt<1><<<32 * 16, 256, 0, stream>>>(attnO, woT, out, 2048, 2048);  // O proj -> fp32
}